// Round 1
// baseline (1633.346 us; speedup 1.0000x reference)
//
#include <hip/hip_runtime.h>

#define V_N 50000
#define E_N 800000
#define PAD 68   // 64 + 4: keeps float4 (16B) alignment, rotates banks by 4/row

// Scratch as device globals (fully rewritten every call; no reliance on prior state)
__device__ float g_h[(size_t)V_N * 64];
__device__ float g_agg[(size_t)V_N * 64];

__device__ __forceinline__ float ssp_f(float x) {
    // softplus(x) - log(2), numerically stable
    float e = __expf(-fabsf(x));
    return fmaxf(x, 0.0f) + __logf(1.0f + e) - 0.6931471805599453f;
}

// 64x64 GEMM micro-kernel: thread computes 4(j) x 4(n) tile.
// Wt/Xt are LDS, layout [k][j]/[k][n] with row stride PAD.
__device__ __forceinline__ void gemm64(const float* __restrict__ Wt,
                                       const float* __restrict__ Xt,
                                       int j0, int n0, float acc[4][4]) {
    #pragma unroll 8
    for (int k = 0; k < 64; ++k) {
        const float4 wv = *(const float4*)&Wt[k * PAD + j0];
        const float4 xv = *(const float4*)&Xt[k * PAD + n0];
        const float w[4] = {wv.x, wv.y, wv.z, wv.w};
        const float x[4] = {xv.x, xv.y, xv.z, xv.w};
        #pragma unroll
        for (int a = 0; a < 4; ++a)
            #pragma unroll
            for (int c = 0; c < 4; ++c)
                acc[a][c] = fmaf(w[a], x[c], acc[a][c]);
    }
}

// Stage a 64x64 fp32 row-major global tile into LDS transposed [col][row] (stride PAD).
// Each thread: 4 x float4 global loads (coalesced), 16 scalar LDS writes.
__device__ __forceinline__ void stage_T(const float* __restrict__ G, float* __restrict__ S,
                                        int t) {
    #pragma unroll
    for (int i = 0; i < 4; ++i) {
        const int idx = i * 256 + t;       // float4 index within 64x64 tile
        const int r  = idx >> 4;           // row 0..63
        const int c4 = (idx & 15) << 2;    // col (multiple of 4)
        const float4 v = ((const float4*)G)[idx];
        S[(c4 + 0) * PAD + r] = v.x;
        S[(c4 + 1) * PAD + r] = v.y;
        S[(c4 + 2) * PAD + r] = v.z;
        S[(c4 + 3) * PAD + r] = v.w;
    }
}

__global__ __launch_bounds__(256)
void zero_agg_kernel() {
    const int i = blockIdx.x * 256 + threadIdx.x;
    if (i < (V_N * 64) / 4)
        ((float4*)g_agg)[i] = make_float4(0.f, 0.f, 0.f, 0.f);
}

// h = node_feats @ Wn^T + bn   (no activation)
__global__ __launch_bounds__(256)
void node_proj_kernel(const float* __restrict__ X, const float* __restrict__ W,
                      const float* __restrict__ b) {
    __shared__ float Xt[64 * PAD];
    __shared__ float Wt[64 * PAD];
    __shared__ float Ys[64 * PAD];
    const int t = threadIdx.x;
    const int base = blockIdx.x * 64;

    stage_T(W, Wt, t);
    #pragma unroll
    for (int i = 0; i < 4; ++i) {
        const int idx = i * 256 + t;
        const int r  = idx >> 4;
        const int c4 = (idx & 15) << 2;
        const int row = base + r;
        float4 v = make_float4(0.f, 0.f, 0.f, 0.f);
        if (row < V_N) v = ((const float4*)X)[(size_t)row * 16 + (idx & 15)];
        Xt[(c4 + 0) * PAD + r] = v.x;
        Xt[(c4 + 1) * PAD + r] = v.y;
        Xt[(c4 + 2) * PAD + r] = v.z;
        Xt[(c4 + 3) * PAD + r] = v.w;
    }
    __syncthreads();

    const int j0 = (t >> 4) << 2, n0 = (t & 15) << 2;
    float acc[4][4] = {};
    gemm64(Wt, Xt, j0, n0, acc);

    const float4 bv = ((const float4*)b)[t >> 4];
    const float bb[4] = {bv.x, bv.y, bv.z, bv.w};
    #pragma unroll
    for (int nn = 0; nn < 4; ++nn) {
        float4 v = make_float4(acc[0][nn] + bb[0], acc[1][nn] + bb[1],
                               acc[2][nn] + bb[2], acc[3][nn] + bb[3]);
        *(float4*)&Ys[(n0 + nn) * PAD + j0] = v;
    }
    __syncthreads();

    #pragma unroll
    for (int i = 0; i < 4; ++i) {
        const int idx = i * 256 + t;
        const int r  = idx >> 4;
        const int c4 = idx & 15;
        const int row = base + r;
        if (row < V_N)
            ((float4*)g_h)[(size_t)row * 16 + c4] = *(const float4*)&Ys[r * PAD + (c4 << 2)];
    }
}

// Per 64-edge tile: w = ssp(ssp(ef@We1^T+be1)@We2^T+be2); scatter h[src]*w into agg[dst]
__global__ __launch_bounds__(256)
void edge_kernel(const float* __restrict__ EF, const int* __restrict__ src,
                 const int* __restrict__ dst,
                 const float* __restrict__ We1, const float* __restrict__ be1,
                 const float* __restrict__ We2, const float* __restrict__ be2) {
    __shared__ float Xt[64 * PAD];
    __shared__ float T1[64 * PAD];
    __shared__ float W1[64 * PAD];
    __shared__ float W2[64 * PAD];
    const int t = threadIdx.x;
    const int e_base = blockIdx.x * 64;

    stage_T(We1, W1, t);
    stage_T(We2, W2, t);
    // edge_feats tile, transposed into Xt[k][e]
    #pragma unroll
    for (int i = 0; i < 4; ++i) {
        const int idx = i * 256 + t;
        const int r  = idx >> 4;
        const int c4 = (idx & 15) << 2;
        const float4 v = ((const float4*)EF)[(size_t)(e_base + r) * 16 + (idx & 15)];
        Xt[(c4 + 0) * PAD + r] = v.x;
        Xt[(c4 + 1) * PAD + r] = v.y;
        Xt[(c4 + 2) * PAD + r] = v.z;
        Xt[(c4 + 3) * PAD + r] = v.w;
    }
    __syncthreads();

    const int jg = t >> 4, ng = t & 15;
    const int j0 = jg << 2, n0 = ng << 2;

    // GEMM1 + bias + ssp -> T1[j][e]
    {
        float acc[4][4] = {};
        gemm64(W1, Xt, j0, n0, acc);
        const float4 bv = ((const float4*)be1)[jg];
        const float bb[4] = {bv.x, bv.y, bv.z, bv.w};
        #pragma unroll
        for (int a = 0; a < 4; ++a) {
            float4 v = make_float4(ssp_f(acc[a][0] + bb[a]), ssp_f(acc[a][1] + bb[a]),
                                   ssp_f(acc[a][2] + bb[a]), ssp_f(acc[a][3] + bb[a]));
            *(float4*)&T1[(j0 + a) * PAD + n0] = v;
        }
    }
    __syncthreads();

    // GEMM2 + bias + ssp, then gather-multiply-scatter
    float acc2[4][4] = {};
    gemm64(W2, T1, j0, n0, acc2);
    const float4 bv2 = ((const float4*)be2)[jg];
    const float bb2[4] = {bv2.x, bv2.y, bv2.z, bv2.w};

    #pragma unroll
    for (int nn = 0; nn < 4; ++nn) {
        const int e = e_base + n0 + nn;
        const int s = src[e];
        const int d = dst[e];
        const float4 hv = *(const float4*)&g_h[(size_t)s * 64 + j0];
        const float h4[4] = {hv.x, hv.y, hv.z, hv.w};
        float* aggp = &g_agg[(size_t)d * 64 + j0];
        #pragma unroll
        for (int a = 0; a < 4; ++a) {
            const float m = h4[a] * ssp_f(acc2[a][nn] + bb2[a]);
            atomicAdd(&aggp[a], m);
        }
    }
}

// out = ssp(agg @ Wc^T + bc) @ Wp^T + bp
__global__ __launch_bounds__(256)
void out_proj_kernel(const float* __restrict__ Wc, const float* __restrict__ bc,
                     const float* __restrict__ Wp, const float* __restrict__ bp,
                     float* __restrict__ Y) {
    __shared__ float Xt[64 * PAD];   // aggT; reused as output staging
    __shared__ float T1[64 * PAD];
    __shared__ float W1[64 * PAD];
    __shared__ float W2[64 * PAD];
    const int t = threadIdx.x;
    const int base = blockIdx.x * 64;

    stage_T(Wc, W1, t);
    stage_T(Wp, W2, t);
    #pragma unroll
    for (int i = 0; i < 4; ++i) {
        const int idx = i * 256 + t;
        const int r  = idx >> 4;
        const int c4 = (idx & 15) << 2;
        const int row = base + r;
        float4 v = make_float4(0.f, 0.f, 0.f, 0.f);
        if (row < V_N) v = ((const float4*)g_agg)[(size_t)row * 16 + (idx & 15)];
        Xt[(c4 + 0) * PAD + r] = v.x;
        Xt[(c4 + 1) * PAD + r] = v.y;
        Xt[(c4 + 2) * PAD + r] = v.z;
        Xt[(c4 + 3) * PAD + r] = v.w;
    }
    __syncthreads();

    const int jg = t >> 4, ng = t & 15;
    const int j0 = jg << 2, n0 = ng << 2;

    {
        float acc[4][4] = {};
        gemm64(W1, Xt, j0, n0, acc);
        const float4 bv = ((const float4*)bc)[jg];
        const float bb[4] = {bv.x, bv.y, bv.z, bv.w};
        #pragma unroll
        for (int a = 0; a < 4; ++a) {
            float4 v = make_float4(ssp_f(acc[a][0] + bb[a]), ssp_f(acc[a][1] + bb[a]),
                                   ssp_f(acc[a][2] + bb[a]), ssp_f(acc[a][3] + bb[a]));
            *(float4*)&T1[(j0 + a) * PAD + n0] = v;
        }
    }
    __syncthreads();

    float acc2[4][4] = {};
    gemm64(W2, T1, j0, n0, acc2);
    const float4 bv2 = ((const float4*)bp)[jg];
    const float bb2[4] = {bv2.x, bv2.y, bv2.z, bv2.w};
    #pragma unroll
    for (int nn = 0; nn < 4; ++nn) {
        float4 v = make_float4(acc2[0][nn] + bb2[0], acc2[1][nn] + bb2[1],
                               acc2[2][nn] + bb2[2], acc2[3][nn] + bb2[3]);
        *(float4*)&Xt[(n0 + nn) * PAD + j0] = v;  // safe: Xt no longer read
    }
    __syncthreads();

    #pragma unroll
    for (int i = 0; i < 4; ++i) {
        const int idx = i * 256 + t;
        const int r  = idx >> 4;
        const int c4 = idx & 15;
        const int row = base + r;
        if (row < V_N)
            ((float4*)Y)[(size_t)row * 16 + c4] = *(const float4*)&Xt[r * PAD + (c4 << 2)];
    }
}

extern "C" void kernel_launch(void* const* d_in, const int* in_sizes, int n_in,
                              void* d_out, int out_size, void* d_ws, size_t ws_size,
                              hipStream_t stream) {
    const float* node = (const float*)d_in[0];
    const float* ef   = (const float*)d_in[1];
    const int*   src  = (const int*)d_in[2];
    const int*   dst  = (const int*)d_in[3];
    const float* Wn   = (const float*)d_in[4];
    const float* bn   = (const float*)d_in[5];
    const float* We1  = (const float*)d_in[6];
    const float* be1  = (const float*)d_in[7];
    const float* We2  = (const float*)d_in[8];
    const float* be2  = (const float*)d_in[9];
    const float* Wc   = (const float*)d_in[10];
    const float* bc   = (const float*)d_in[11];
    const float* Wp   = (const float*)d_in[12];
    const float* bp   = (const float*)d_in[13];
    float* out = (float*)d_out;

    zero_agg_kernel<<<(V_N * 64 / 4 + 255) / 256, 256, 0, stream>>>();
    node_proj_kernel<<<(V_N + 63) / 64, 256, 0, stream>>>(node, Wn, bn);
    edge_kernel<<<E_N / 64, 256, 0, stream>>>(ef, src, dst, We1, be1, We2, be2);
    out_proj_kernel<<<(V_N + 63) / 64, 256, 0, stream>>>(Wc, bc, Wp, bp, out);
}

// Round 2
// 729.872 us; speedup vs baseline: 2.2379x; 2.2379x over previous
//
#include <hip/hip_runtime.h>

#define V_N 50000
#define E_N 800000
#define PAD 68   // 64 + 4: keeps float4 (16B) alignment, rotates banks by 4/row

// Scratch as device globals (fully rewritten every call; no reliance on prior state)
__device__ float g_h[(size_t)V_N * 64];
__device__ float g_agg[(size_t)V_N * 64];
__device__ float g_m[(size_t)E_N * 64];      // per-edge messages, 204.8 MB
__device__ int   g_count[V_N];
__device__ int   g_rowstart[V_N + 1];
__device__ int   g_cursor[V_N];
__device__ int   g_perm[E_N];

__device__ __forceinline__ float ssp_f(float x) {
    // softplus(x) - log(2), numerically stable
    float e = __expf(-fabsf(x));
    return fmaxf(x, 0.0f) + __logf(1.0f + e) - 0.6931471805599453f;
}

// 64x64 GEMM micro-kernel: thread computes 4(j) x 4(n) tile.
// Wt/Xt are LDS, layout [k][j]/[k][n] with row stride PAD.
__device__ __forceinline__ void gemm64(const float* __restrict__ Wt,
                                       const float* __restrict__ Xt,
                                       int j0, int n0, float acc[4][4]) {
    #pragma unroll 8
    for (int k = 0; k < 64; ++k) {
        const float4 wv = *(const float4*)&Wt[k * PAD + j0];
        const float4 xv = *(const float4*)&Xt[k * PAD + n0];
        const float w[4] = {wv.x, wv.y, wv.z, wv.w};
        const float x[4] = {xv.x, xv.y, xv.z, xv.w};
        #pragma unroll
        for (int a = 0; a < 4; ++a)
            #pragma unroll
            for (int c = 0; c < 4; ++c)
                acc[a][c] = fmaf(w[a], x[c], acc[a][c]);
    }
}

// Stage a 64x64 fp32 row-major global tile into LDS transposed [col][row] (stride PAD).
__device__ __forceinline__ void stage_T(const float* __restrict__ G, float* __restrict__ S,
                                        int t) {
    #pragma unroll
    for (int i = 0; i < 4; ++i) {
        const int idx = i * 256 + t;       // float4 index within 64x64 tile
        const int r  = idx >> 4;           // row 0..63
        const int c4 = (idx & 15) << 2;    // col (multiple of 4)
        const float4 v = ((const float4*)G)[idx];
        S[(c4 + 0) * PAD + r] = v.x;
        S[(c4 + 1) * PAD + r] = v.y;
        S[(c4 + 2) * PAD + r] = v.z;
        S[(c4 + 3) * PAD + r] = v.w;
    }
}

__global__ __launch_bounds__(256)
void zero_count_kernel() {
    const int i = blockIdx.x * 256 + threadIdx.x;
    if (i < V_N) g_count[i] = 0;
}

__global__ __launch_bounds__(256)
void hist_kernel(const int* __restrict__ dst) {
    const int e = blockIdx.x * 256 + threadIdx.x;
    if (e < E_N) atomicAdd(&g_count[dst[e]], 1);
}

// Single-block exclusive scan of g_count -> g_rowstart (+g_cursor copy).
__global__ __launch_bounds__(1024)
void scan_kernel() {
    __shared__ int wsum[16];
    __shared__ int s_carry;
    const int t = threadIdx.x;
    const int lane = t & 63;
    const int wid = t >> 6;
    if (t == 0) s_carry = 0;
    __syncthreads();
    for (int base = 0; base < V_N; base += 1024) {
        const int i = base + t;
        int v = (i < V_N) ? g_count[i] : 0;
        // intra-wave inclusive scan (wave64 shuffle)
        int s = v;
        #pragma unroll
        for (int off = 1; off < 64; off <<= 1) {
            int n = __shfl_up(s, off, 64);
            if (lane >= off) s += n;
        }
        if (lane == 63) wsum[wid] = s;
        __syncthreads();
        const int carry = s_carry;
        int woff = 0;
        #pragma unroll
        for (int w = 0; w < 16; ++w)
            if (w < wid) woff += wsum[w];
        const int excl = carry + woff + (s - v);
        if (i < V_N) { g_rowstart[i] = excl; g_cursor[i] = excl; }
        __syncthreads();                 // all reads of s_carry/wsum done
        if (t == 1023) s_carry = carry + woff + s;
        __syncthreads();
    }
    if (t == 0) g_rowstart[V_N] = s_carry;
}

__global__ __launch_bounds__(256)
void scatter_kernel(const int* __restrict__ dst) {
    const int e = blockIdx.x * 256 + threadIdx.x;
    if (e < E_N) {
        const int pos = atomicAdd(&g_cursor[dst[e]], 1);
        g_perm[pos] = e;
    }
}

// h = node_feats @ Wn^T + bn   (no activation)
__global__ __launch_bounds__(256)
void node_proj_kernel(const float* __restrict__ X, const float* __restrict__ W,
                      const float* __restrict__ b) {
    __shared__ float Xt[64 * PAD];
    __shared__ float Wt[64 * PAD];
    __shared__ float Ys[64 * PAD];
    const int t = threadIdx.x;
    const int base = blockIdx.x * 64;

    stage_T(W, Wt, t);
    #pragma unroll
    for (int i = 0; i < 4; ++i) {
        const int idx = i * 256 + t;
        const int r  = idx >> 4;
        const int c4 = (idx & 15) << 2;
        const int row = base + r;
        float4 v = make_float4(0.f, 0.f, 0.f, 0.f);
        if (row < V_N) v = ((const float4*)X)[(size_t)row * 16 + (idx & 15)];
        Xt[(c4 + 0) * PAD + r] = v.x;
        Xt[(c4 + 1) * PAD + r] = v.y;
        Xt[(c4 + 2) * PAD + r] = v.z;
        Xt[(c4 + 3) * PAD + r] = v.w;
    }
    __syncthreads();

    const int j0 = (t >> 4) << 2, n0 = (t & 15) << 2;
    float acc[4][4] = {};
    gemm64(Wt, Xt, j0, n0, acc);

    const float4 bv = ((const float4*)b)[t >> 4];
    const float bb[4] = {bv.x, bv.y, bv.z, bv.w};
    #pragma unroll
    for (int nn = 0; nn < 4; ++nn) {
        float4 v = make_float4(acc[0][nn] + bb[0], acc[1][nn] + bb[1],
                               acc[2][nn] + bb[2], acc[3][nn] + bb[3]);
        *(float4*)&Ys[(n0 + nn) * PAD + j0] = v;
    }
    __syncthreads();

    #pragma unroll
    for (int i = 0; i < 4; ++i) {
        const int idx = i * 256 + t;
        const int r  = idx >> 4;
        const int c4 = idx & 15;
        const int row = base + r;
        if (row < V_N)
            ((float4*)g_h)[(size_t)row * 16 + c4] = *(const float4*)&Ys[r * PAD + (c4 << 2)];
    }
}

// Per 64-edge tile: w = ssp(ssp(ef@We1^T+be1)@We2^T+be2); m[e] = h[src[e]] * w  (coalesced write)
__global__ __launch_bounds__(256)
void edge_pass1(const float* __restrict__ EF, const int* __restrict__ src,
                const float* __restrict__ We1, const float* __restrict__ be1,
                const float* __restrict__ We2, const float* __restrict__ be2) {
    __shared__ float Xt[64 * PAD];   // edge tile [k][e]; reused as T1 [j][e]
    __shared__ float W1[64 * PAD];
    __shared__ float W2[64 * PAD];
    const int t = threadIdx.x;
    const int e_base = blockIdx.x * 64;

    stage_T(We1, W1, t);
    stage_T(We2, W2, t);
    #pragma unroll
    for (int i = 0; i < 4; ++i) {
        const int idx = i * 256 + t;
        const int r  = idx >> 4;
        const int c4 = (idx & 15) << 2;
        const float4 v = ((const float4*)EF)[(size_t)(e_base + r) * 16 + (idx & 15)];
        Xt[(c4 + 0) * PAD + r] = v.x;
        Xt[(c4 + 1) * PAD + r] = v.y;
        Xt[(c4 + 2) * PAD + r] = v.z;
        Xt[(c4 + 3) * PAD + r] = v.w;
    }
    __syncthreads();

    const int jg = t >> 4, ng = t & 15;
    const int j0 = jg << 2, n0 = ng << 2;

    // GEMM1 + bias + ssp (kept in registers)
    float r1[4][4];
    {
        float acc[4][4] = {};
        gemm64(W1, Xt, j0, n0, acc);
        const float4 bv = ((const float4*)be1)[jg];
        const float bb[4] = {bv.x, bv.y, bv.z, bv.w};
        #pragma unroll
        for (int a = 0; a < 4; ++a)
            #pragma unroll
            for (int c = 0; c < 4; ++c)
                r1[a][c] = ssp_f(acc[a][c] + bb[a]);
    }
    __syncthreads();   // everyone done reading Xt
    #pragma unroll
    for (int a = 0; a < 4; ++a)
        *(float4*)&Xt[(j0 + a) * PAD + n0] =
            make_float4(r1[a][0], r1[a][1], r1[a][2], r1[a][3]);
    __syncthreads();

    // GEMM2 + bias + ssp, gather h[src], write m coalesced
    float acc2[4][4] = {};
    gemm64(W2, Xt, j0, n0, acc2);
    const float4 bv2 = ((const float4*)be2)[jg];
    const float bb2[4] = {bv2.x, bv2.y, bv2.z, bv2.w};

    #pragma unroll
    for (int nn = 0; nn < 4; ++nn) {
        const int e = e_base + n0 + nn;
        const int s = src[e];
        const float4 hv = *(const float4*)&g_h[(size_t)s * 64 + j0];
        float4 o;
        o.x = hv.x * ssp_f(acc2[0][nn] + bb2[0]);
        o.y = hv.y * ssp_f(acc2[1][nn] + bb2[1]);
        o.z = hv.z * ssp_f(acc2[2][nn] + bb2[2]);
        o.w = hv.w * ssp_f(acc2[3][nn] + bb2[3]);
        *(float4*)&g_m[(size_t)e * 64 + j0] = o;
    }
}

// One wave per node: lane = feature, sum m rows via CSR. No atomics.
__global__ __launch_bounds__(256)
void aggregate_kernel() {
    const int t = threadIdx.x;
    const int lane = t & 63;
    const int wid = t >> 6;
    const int v = blockIdx.x * 4 + wid;
    if (v >= V_N) return;
    const int beg = g_rowstart[v];
    const int end = g_rowstart[v + 1];
    float acc = 0.f;
    int i = beg;
    for (; i + 1 < end; i += 2) {
        const int e0 = g_perm[i];
        const int e1 = g_perm[i + 1];
        const float a = g_m[(size_t)e0 * 64 + lane];
        const float b = g_m[(size_t)e1 * 64 + lane];
        acc += a;
        acc += b;
    }
    if (i < end) acc += g_m[(size_t)g_perm[i] * 64 + lane];
    g_agg[(size_t)v * 64 + lane] = acc;
}

// out = ssp(agg @ Wc^T + bc) @ Wp^T + bp
__global__ __launch_bounds__(256)
void out_proj_kernel(const float* __restrict__ Wc, const float* __restrict__ bc,
                     const float* __restrict__ Wp, const float* __restrict__ bp,
                     float* __restrict__ Y) {
    __shared__ float Xt[64 * PAD];   // aggT; reused as output staging
    __shared__ float T1[64 * PAD];
    __shared__ float W1[64 * PAD];
    __shared__ float W2[64 * PAD];
    const int t = threadIdx.x;
    const int base = blockIdx.x * 64;

    stage_T(Wc, W1, t);
    stage_T(Wp, W2, t);
    #pragma unroll
    for (int i = 0; i < 4; ++i) {
        const int idx = i * 256 + t;
        const int r  = idx >> 4;
        const int c4 = (idx & 15) << 2;
        const int row = base + r;
        float4 v = make_float4(0.f, 0.f, 0.f, 0.f);
        if (row < V_N) v = ((const float4*)g_agg)[(size_t)row * 16 + (idx & 15)];
        Xt[(c4 + 0) * PAD + r] = v.x;
        Xt[(c4 + 1) * PAD + r] = v.y;
        Xt[(c4 + 2) * PAD + r] = v.z;
        Xt[(c4 + 3) * PAD + r] = v.w;
    }
    __syncthreads();

    const int jg = t >> 4, ng = t & 15;
    const int j0 = jg << 2, n0 = ng << 2;

    {
        float acc[4][4] = {};
        gemm64(W1, Xt, j0, n0, acc);
        const float4 bv = ((const float4*)bc)[jg];
        const float bb[4] = {bv.x, bv.y, bv.z, bv.w};
        #pragma unroll
        for (int a = 0; a < 4; ++a) {
            float4 v = make_float4(ssp_f(acc[a][0] + bb[a]), ssp_f(acc[a][1] + bb[a]),
                                   ssp_f(acc[a][2] + bb[a]), ssp_f(acc[a][3] + bb[a]));
            *(float4*)&T1[(j0 + a) * PAD + n0] = v;
        }
    }
    __syncthreads();

    float acc2[4][4] = {};
    gemm64(W2, T1, j0, n0, acc2);
    const float4 bv2 = ((const float4*)bp)[jg];
    const float bb2[4] = {bv2.x, bv2.y, bv2.z, bv2.w};
    #pragma unroll
    for (int nn = 0; nn < 4; ++nn) {
        float4 v = make_float4(acc2[0][nn] + bb2[0], acc2[1][nn] + bb2[1],
                               acc2[2][nn] + bb2[2], acc2[3][nn] + bb2[3]);
        *(float4*)&Xt[(n0 + nn) * PAD + j0] = v;  // safe: Xt no longer read
    }
    __syncthreads();

    #pragma unroll
    for (int i = 0; i < 4; ++i) {
        const int idx = i * 256 + t;
        const int r  = idx >> 4;
        const int c4 = idx & 15;
        const int row = base + r;
        if (row < V_N)
            ((float4*)Y)[(size_t)row * 16 + c4] = *(const float4*)&Xt[r * PAD + (c4 << 2)];
    }
}

extern "C" void kernel_launch(void* const* d_in, const int* in_sizes, int n_in,
                              void* d_out, int out_size, void* d_ws, size_t ws_size,
                              hipStream_t stream) {
    const float* node = (const float*)d_in[0];
    const float* ef   = (const float*)d_in[1];
    const int*   src  = (const int*)d_in[2];
    const int*   dst  = (const int*)d_in[3];
    const float* Wn   = (const float*)d_in[4];
    const float* bn   = (const float*)d_in[5];
    const float* We1  = (const float*)d_in[6];
    const float* be1  = (const float*)d_in[7];
    const float* We2  = (const float*)d_in[8];
    const float* be2  = (const float*)d_in[9];
    const float* Wc   = (const float*)d_in[10];
    const float* bc   = (const float*)d_in[11];
    const float* Wp   = (const float*)d_in[12];
    const float* bp   = (const float*)d_in[13];
    float* out = (float*)d_out;

    // CSR build (int atomics only)
    zero_count_kernel<<<(V_N + 255) / 256, 256, 0, stream>>>();
    hist_kernel<<<(E_N + 255) / 256, 256, 0, stream>>>(dst);
    scan_kernel<<<1, 1024, 0, stream>>>();
    scatter_kernel<<<(E_N + 255) / 256, 256, 0, stream>>>(dst);

    // h = node @ Wn^T + bn
    node_proj_kernel<<<(V_N + 63) / 64, 256, 0, stream>>>(node, Wn, bn);

    // m[e] = h[src] * edge_mlp(ef)   (coalesced write, no atomics)
    edge_pass1<<<E_N / 64, 256, 0, stream>>>(ef, src, We1, be1, We2, be2);

    // agg[v] = sum of m rows (CSR gather, no atomics)
    aggregate_kernel<<<(V_N + 3) / 4, 256, 0, stream>>>();

    // out = ssp(agg @ Wc^T + bc) @ Wp^T + bp
    out_proj_kernel<<<(V_N + 63) / 64, 256, 0, stream>>>(Wc, bc, Wp, bp, out);
}